// Round 9
// baseline (872.437 us; speedup 1.0000x reference)
//
#include <hip/hip_runtime.h>
#include <cstdint>

#define NB 32
#define NBW 4                      // batch elements per workgroup (b-eighth)
#define IC 2048
#define IK 16
#define OC 64
#define OD 32
#define PARTBLK (NBW*OC*OD)        // 8192 floats (32 KB) per wg partial
#define NCHUNK 128                 // i-chunks; grid = 8*NCHUNK
#define NTW 8                      // twins per i-chunk

typedef __fp16 h2 __attribute__((ext_vector_type(2)));

__device__ __forceinline__ h2 pk2(float a, float b) {
#if __has_builtin(__builtin_amdgcn_cvt_pkrtz)
  return __builtin_amdgcn_cvt_pkrtz(a, b);
#else
  h2 r; r.x = (__fp16)a; r.y = (__fp16)b; return r;
#endif
}

__device__ __forceinline__ float fdot2a(h2 a, h2 b, float c) {
#if __has_builtin(__builtin_amdgcn_fdot2)
  return __builtin_amdgcn_fdot2(a, b, c, false);
#else
  return c + (float)a.x*(float)b.x + (float)a.y*(float)b.y;
#endif
}

__device__ __forceinline__ h2 bch2(unsigned int u) { return __builtin_bit_cast(h2, u); }
__device__ __forceinline__ unsigned int bcu(h2 v)  { return __builtin_bit_cast(unsigned int, v); }

// Routing pass, s-tile in LDS.
// R7: NBW=16 -> 1 wg/CU, latency-bound. R8: NBW=8 -> 2 wg/CU, 262us, VALU 30%,
// occ 45% -> still latency-bound. Now NBW=4: LDS 34 KB -> 4 wg/CU, 8 waves/SIMD.
// WMODE: 0 = read f32 W; 1 = read f32 W and store packed-f16 Wh (bq==0 only);
//        2 = read f16 Wh (half the bytes/loads, no pk2 in hot loop).
// 8 twins (b-eighths) of one i-chunk co-located on one XCD (bid%8 decode) so
// the per-ci W chunk (2 MB f32 / 1 MB f16) is served by that XCD's L2.
// 512 threads: o = t>>3, dq = t&7 (d-quad). XOR quad-swizzle on s_lds rows.
template<int ITER, int WMODE>
__global__ __launch_bounds__(512)
void caps_pass(const float* __restrict__ xg, const float* __restrict__ Wg,
               unsigned int* __restrict__ Whg,
               const float* __restrict__ vin, const float* __restrict__ bin,
               float* __restrict__ bout, float* __restrict__ part,
               int chunk, int nchunk)
{
  __shared__ float s_lds[NBW*OC*OD];                    // 32 KB
  __shared__ __align__(16) unsigned int x_h[8][NBW][8]; // 1 KB (f16x2 x)
  __shared__ float agr_s[NBW][OC];                      // 1 KB

  const int t    = threadIdx.x;
  const int o    = t >> 3;          // 0..63
  const int dq   = t & 7;           // d-quad, d = dq*4+j
  const int d0   = dq * 4;
  const int lane = t & 63;

  // decode (ci, bq): bid%8 = XCD (round-robin heuristic); the 8 twins of one
  // ci are consecutive slots on one XCD -> share its L2 for the W stream.
  const int bid = blockIdx.x;
  int ci, bq;
  if ((nchunk & 7) == 0) {
    const int xcd = bid & 7, slot = bid >> 3;
    ci = xcd * (nchunk >> 3) + (slot >> 3);
    bq = slot & 7;
  } else { ci = bid >> 3; bq = bid & 7; }
  const int i0  = ci * chunk;
  const int bg0 = bq * NBW;
  const int qp  = dq ^ (o & 7);     // swizzled quad (bank-conflict break)
  const int sbase = o * OD + qp * 4;

  for (int idx = t; idx < NBW*OC*OD; idx += 512) s_lds[idx] = 0.f;

  for (int g = 0; g < chunk; g += 8) {
    const int ibase = i0 + g;
    // stage x[bg0..+4, ibase..+8, :] packed f16 — 128 float4 over 512 thr
    if (t < 128) {
      const int b = t >> 5, rem = t & 31, ii = rem >> 2, k4 = rem & 3;
      const float4 xv = *(const float4*)&xg[((size_t)(bg0 + b)*IC + ibase + ii)*IK + k4*4];
      x_h[ii][b][k4*2]   = bcu(pk2(xv.x, xv.y));
      x_h[ii][b][k4*2+1] = bcu(pk2(xv.z, xv.w));
    }
    __syncthreads();

#pragma unroll 1
    for (int ii = 0; ii < 8; ++ii) {
      const int i = ibase + ii;
      h2 wh[4][8];
      if constexpr (WMODE == 2) {
        // W f16: 128 B contiguous per thread = 8 uint4
        const uint4* Wp = (const uint4*)(Whg + (((size_t)i*OC + o)*OD + d0)*(IK/2));
#pragma unroll
        for (int j = 0; j < 4; ++j) {
          const uint4 wa = Wp[j*2], wb = Wp[j*2 + 1];
          wh[j][0]=bch2(wa.x); wh[j][1]=bch2(wa.y); wh[j][2]=bch2(wa.z); wh[j][3]=bch2(wa.w);
          wh[j][4]=bch2(wb.x); wh[j][5]=bch2(wb.y); wh[j][6]=bch2(wb.z); wh[j][7]=bch2(wb.w);
        }
      } else {
        // W f32: 256 B contiguous per thread -> packed f16
        const float4* Wp = (const float4*)(Wg + (((size_t)i*OC + o)*OD + d0)*IK);
#pragma unroll
        for (int j = 0; j < 4; ++j)
#pragma unroll
          for (int q = 0; q < 4; ++q) {
            const float4 w4 = Wp[j*4 + q];
            wh[j][q*2]   = pk2(w4.x, w4.y);
            wh[j][q*2+1] = pk2(w4.z, w4.w);
          }
        if constexpr (WMODE == 1) {
          if (bq == 0) {   // wave-uniform: one twin writes the f16 copy
            uint4* dst = (uint4*)(Whg + (((size_t)i*OC + o)*OD + d0)*(IK/2));
#pragma unroll
            for (int j = 0; j < 4; ++j) {
              uint4 pa, pb;
              pa.x=bcu(wh[j][0]); pa.y=bcu(wh[j][1]); pa.z=bcu(wh[j][2]); pa.w=bcu(wh[j][3]);
              pb.x=bcu(wh[j][4]); pb.y=bcu(wh[j][5]); pb.z=bcu(wh[j][6]); pb.w=bcu(wh[j][7]);
              dst[j*2]   = pa;
              dst[j*2+1] = pb;
            }
          }
        }
      }

      if (ITER == 0) {
#pragma unroll
        for (int b = 0; b < NBW; ++b) {
          const uint4* xp = (const uint4*)&x_h[ii][b][0];
          const uint4 xa = xp[0], xb4 = xp[1];
          const h2 xh[8] = {bch2(xa.x),bch2(xa.y),bch2(xa.z),bch2(xa.w),
                            bch2(xb4.x),bch2(xb4.y),bch2(xb4.z),bch2(xb4.w)};
          float a0=0.f, a1=0.f, a2=0.f, a3=0.f;
#pragma unroll
          for (int q = 0; q < 8; ++q) {
            a0 = fdot2a(wh[0][q], xh[q], a0);
            a1 = fdot2a(wh[1][q], xh[q], a1);
            a2 = fdot2a(wh[2][q], xh[q], a2);
            a3 = fdot2a(wh[3][q], xh[q], a3);
          }
          float4* sp = (float4*)&s_lds[b*(OC*OD) + sbase];
          float4 sv = *sp;
          sv.x += a0; sv.y += a1; sv.z += a2; sv.w += a3;
          *sp = sv;
        }
      } else {
        float usav[NBW][4];
#pragma unroll
        for (int b = 0; b < NBW; ++b) {
          const uint4* xp = (const uint4*)&x_h[ii][b][0];
          const uint4 xa = xp[0], xb4 = xp[1];
          const h2 xh[8] = {bch2(xa.x),bch2(xa.y),bch2(xa.z),bch2(xa.w),
                            bch2(xb4.x),bch2(xb4.y),bch2(xb4.z),bch2(xb4.w)};
          float u0=0.f, u1=0.f, u2=0.f, u3=0.f;
#pragma unroll
          for (int q = 0; q < 8; ++q) {
            u0 = fdot2a(wh[0][q], xh[q], u0);
            u1 = fdot2a(wh[1][q], xh[q], u1);
            u2 = fdot2a(wh[2][q], xh[q], u2);
            u3 = fdot2a(wh[3][q], xh[q], u3);
          }
          usav[b][0]=u0; usav[b][1]=u1; usav[b][2]=u2; usav[b][3]=u3;
          // agreement = sum_d u*v, reduce over the 8 dq lanes (same o)
          const float4 vv = *(const float4*)&vin[((size_t)(bg0+b)*OC + o)*OD + d0];
          float ap = u0*vv.x + u1*vv.y + u2*vv.z + u3*vv.w;
          ap += __shfl_xor(ap, 1);
          ap += __shfl_xor(ap, 2);
          ap += __shfl_xor(ap, 4);
          if (dq == 0) {
            float bn = ap;
            if (ITER == 2) bn += bin[((size_t)(bg0+b)*IC + i)*OC + o];
            if (ITER == 1) bout[((size_t)(bg0+b)*IC + i)*OC + o] = bn;
            agr_s[b][o] = bn;
          }
        }
        __syncthreads();
        // wave-redundant softmax over the 64 o's + s accumulation in LDS
#pragma unroll
        for (int b = 0; b < NBW; ++b) {
          const float a = agr_s[b][lane];
          float m = a;
#pragma unroll
          for (int off = 1; off < 64; off <<= 1) m = fmaxf(m, __shfl_xor(m, off));
          const float e = __expf(a - m);
          float se = e;
#pragma unroll
          for (int off = 1; off < 64; off <<= 1) se += __shfl_xor(se, off);
          const float cl = e / se;          // c for o = lane
          const float cm = __shfl(cl, o);   // c for my o
          float4* sp = (float4*)&s_lds[b*(OC*OD) + sbase];
          float4 sv = *sp;
          sv.x += cm*usav[b][0]; sv.y += cm*usav[b][1];
          sv.z += cm*usav[b][2]; sv.w += cm*usav[b][3];
          *sp = sv;
        }
        __syncthreads();   // agr_s rows reused next ii: order reads vs writes
      }
    }
    __syncthreads();       // protect x_h restage (and s zero-init on g==0)
  }

  // flush per-wg partial s (coalesced float4, un-swizzled to logical d)
  const float scale = (ITER == 0) ? (1.0f/64.0f) : 1.0f;
  float* pp = part + (size_t)(ci*NTW + bq) * PARTBLK;
#pragma unroll
  for (int b = 0; b < NBW; ++b) {
    float4 sv = *(float4*)&s_lds[b*(OC*OD) + sbase];
    float4 st;
    st.x = sv.x*scale; st.y = sv.y*scale; st.z = sv.z*scale; st.w = sv.w*scale;
    *(float4*)&pp[((size_t)b*OC + o)*OD + d0] = st;
  }
}

// Sum partials over i-chunks and apply squash. One 64-thr block per (b,o):
// lanes 0..31 = d; the two 32-lane halves split the chunk range.
__global__ __launch_bounds__(64)
void caps_reduce(const float* __restrict__ part, int nchunk, float* __restrict__ vout)
{
  const int r  = blockIdx.x;           // b*OC + o, 0..2047
  const int b  = r >> 6, o = r & 63;
  const int bq = b >> 2, bl = b & 3;   // b-eighth, local b
  const int d  = threadIdx.x & 31;
  const int h  = threadIdx.x >> 5;
  const size_t cellp = ((size_t)(bl*OC + o))*OD + d;
  const int half = nchunk >> 1;
  const float* p = part + ((size_t)(h*half)*NTW + bq)*PARTBLK + cellp;
  float s = 0.f;
#pragma unroll 4
  for (int w = 0; w < half; ++w) s += p[(size_t)w*NTW*PARTBLK];
  s += __shfl_xor(s, 32);              // combine the two halves
  float n2 = s*s;
#pragma unroll
  for (int off = 1; off < 32; off <<= 1) n2 += __shfl_xor(n2, off);
  const float n = sqrtf(n2);
  const float f = n2 / ((1.f + n2)*(n + 1e-8f));   // squash, matches ref
  if (h == 0) vout[(size_t)r*OD + d] = s*f;
}

extern "C" void kernel_launch(void* const* d_in, const int* in_sizes, int n_in,
                              void* d_out, int out_size, void* d_ws, size_t ws_size,
                              hipStream_t stream)
{
  const float* xg = (const float*)d_in[0];
  const float* Wg = (const float*)d_in[1];
  float* out = (float*)d_out;

  const size_t bbuf_bytes = (size_t)NB*IC*OC*sizeof(float);     // 16 MB logits
  const size_t v_bytes    = (size_t)NB*OC*OD*sizeof(float);     // 256 KB
  const size_t wh_bytes   = (size_t)IC*OC*OD*IK*sizeof(short);  // 128 MB f16 W
  int nchunk = NCHUNK;                                          // part = 32 MB
  while (nchunk > 16 &&
         ((size_t)nchunk*NTW*PARTBLK*sizeof(float) + bbuf_bytes + v_bytes) > ws_size)
    nchunk >>= 1;
  const int chunk = IC / nchunk;
  const int nwg = nchunk * NTW;
  const size_t part_bytes = (size_t)nwg*PARTBLK*sizeof(float);

  float* part = (float*)d_ws;
  float* bbuf = (float*)((char*)d_ws + part_bytes);
  float* vbuf = (float*)((char*)bbuf + bbuf_bytes);
  unsigned int* whb = (unsigned int*)((char*)vbuf + v_bytes);
  const bool useWh = (part_bytes + bbuf_bytes + v_bytes + wh_bytes) <= ws_size;

  if (useWh) {
    // iter 1 (c = 1/64): read f32 W, bq==0 twins write packed-f16 Wh
    caps_pass<0,1><<<nwg, 512, 0, stream>>>(xg, Wg, whb, nullptr, nullptr, nullptr, part, chunk, nchunk);
    caps_reduce<<<NB*OC, 64, 0, stream>>>(part, nchunk, vbuf);
    // iters 2,3 read the half-size f16 Wh
    caps_pass<1,2><<<nwg, 512, 0, stream>>>(xg, Wg, whb, vbuf, nullptr, bbuf, part, chunk, nchunk);
    caps_reduce<<<NB*OC, 64, 0, stream>>>(part, nchunk, vbuf);
    caps_pass<2,2><<<nwg, 512, 0, stream>>>(xg, Wg, whb, vbuf, bbuf, nullptr, part, chunk, nchunk);
    caps_reduce<<<NB*OC, 64, 0, stream>>>(part, nchunk, out);
  } else {
    caps_pass<0,0><<<nwg, 512, 0, stream>>>(xg, Wg, nullptr, nullptr, nullptr, nullptr, part, chunk, nchunk);
    caps_reduce<<<NB*OC, 64, 0, stream>>>(part, nchunk, vbuf);
    caps_pass<1,0><<<nwg, 512, 0, stream>>>(xg, Wg, nullptr, vbuf, nullptr, bbuf, part, chunk, nchunk);
    caps_reduce<<<NB*OC, 64, 0, stream>>>(part, nchunk, vbuf);
    caps_pass<2,0><<<nwg, 512, 0, stream>>>(xg, Wg, nullptr, vbuf, bbuf, nullptr, part, chunk, nchunk);
    caps_reduce<<<NB*OC, 64, 0, stream>>>(part, nchunk, out);
  }
}

// Round 10
// 361.742 us; speedup vs baseline: 2.4118x; 2.4118x over previous
//
#include <hip/hip_runtime.h>
#include <cstdint>

#define NB 32
#define NBW 16
#define IC 2048
#define IK 16
#define OC 64
#define OD 32
#define ODF (OC*OD)          // 2048 flattened od
#define NCH 128              // i-chunks
#define CHUNK (IC/NCH)       // 16
#define PARTBLK (NBW*ODF)    // 32768 floats per slot
#define NSLOT (NCH*2)        // 256 wgs

typedef __fp16 h2 __attribute__((ext_vector_type(2)));
typedef __fp16 h8 __attribute__((ext_vector_type(8)));
typedef float  f4 __attribute__((ext_vector_type(4)));

__device__ __forceinline__ h2 pk2(float a, float b) {
#if __has_builtin(__builtin_amdgcn_cvt_pkrtz)
  return __builtin_amdgcn_cvt_pkrtz(a, b);
#else
  h2 r; r.x = (__fp16)a; r.y = (__fp16)b; return r;
#endif
}
__device__ __forceinline__ unsigned int bcu(h2 v){ return __builtin_bit_cast(unsigned int, v); }
__device__ __forceinline__ h2 bch2(unsigned int u){ return __builtin_bit_cast(h2, u); }
__device__ __forceinline__ h8 bch8(uint4 u){ return __builtin_bit_cast(h8, u); }

__device__ __forceinline__ f4 mfma_16x16x32(h8 a, h8 b, f4 c) {
  return __builtin_amdgcn_mfma_f32_16x16x32_f16(a, b, c, 0, 0, 0);
}

// MFMA routing pass. R8/R9 lesson: b-split twins amplify W traffic through
// L2/L3 (8x) and VALU-dot is issue-bound. Here wg = 1024 thr (16 waves)
// covers ALL 128 od-tiles x 16 b per i (only 2 twins -> 2x W traffic).
// Per i: u_hat tile = mfma_f32_16x16x32_f16(W-frag, x-frag).
//   A: lane row = l&15 (od within tile), k = (l>>4)*8+j.  B: col = l&15 (b).
//   D: col = l&15 (b), row = (l>>4)*4+reg (d-quad)  [verified layout, m89].
// ITER=0: two i's merged per MFMA (K=32 = 2x16), acc in regs over the whole
//   chunk, ~13 KB LDS -> 2 wg/CU. ITER>0: zero-padded upper K (lanes>=32),
//   u saved packed f16, per-b softmax by wave w==b, s in 128 KB LDS.
template<int ITER>
__global__ __launch_bounds__(1024)
void caps_pass(const float* __restrict__ xg, const float* __restrict__ Wg,
               const float* __restrict__ vin, const float* __restrict__ binT,
               float* __restrict__ boutT, float* __restrict__ part)
{
  __shared__ uint4 x_h[8][2][16];                         // 4 KB packed-f16 x
  __shared__ float agr[OC][17];                           // 4.3 KB (+1 pad)
  __shared__ float c_s[NBW][68];                          // 4.3 KB (+4 pad)
  __shared__ f4 s_lds[(ITER==0) ? 1 : (128*4*16)];        // 128 KB (ITER>0)

  const int t  = threadIdx.x;       // 0..1023
  const int w  = t >> 6;            // wave 0..15
  const int l  = t & 63;
  const int lb = l & 15;            // tile col (b) / A row (od)
  const int lg = l >> 4;            // lane group 0..3

  // bid%8 = XCD; twin pair (bh 0/1) of one ci lands on the same XCD's L2.
  const int bid  = blockIdx.x;
  const int slot = bid >> 3;        // 0..31
  const int bh   = slot & 1;
  const int ci   = (bid & 7) * 16 + (slot >> 1);   // 0..127
  const int i0   = ci * CHUNK;
  const int bg0  = bh * NBW;
  const f4 zf = {0.f, 0.f, 0.f, 0.f};

  f4 acc[8];
  if (ITER == 0) {
#pragma unroll
    for (int q = 0; q < 8; ++q) acc[q] = zf;
  } else {
    for (int idx = t; idx < 128*4*16; idx += 1024) s_lds[idx] = zf;
  }

  for (int g8 = 0; g8 < CHUNK; g8 += 8) {
    if (g8) __syncthreads();        // x_h readers of prev group done
    if (t < 256) {                  // stage x[16 b][8 i][16 k] as f16
      const int si = t >> 5, kc = (t >> 4) & 1, sb = t & 15;
      const float* xp = &xg[((size_t)(bg0 + sb)*IC + (i0 + g8 + si))*IK + kc*8];
      const float4 xa = *(const float4*)xp;
      const float4 xb = *(const float4*)(xp + 4);
      uint4 u;
      u.x = bcu(pk2(xa.x, xa.y)); u.y = bcu(pk2(xa.z, xa.w));
      u.z = bcu(pk2(xb.x, xb.y)); u.w = bcu(pk2(xb.z, xb.w));
      x_h[si][kc][sb] = u;
    }
    __syncthreads();

    if (ITER == 0) {
#pragma unroll 1
      for (int p = 0; p < 4; ++p) {           // pair of i per MFMA (K=32)
        const int isel = lg >> 1, kc = lg & 1;
        const int il = p*2 + isel;            // group-local i
        const h8 B = bch8(x_h[il][kc][lb]);
        const size_t wbase = ((size_t)(i0 + g8 + il)*ODF + lb)*IK + kc*8;
#pragma unroll
        for (int tt = 0; tt < 8; ++tt) {
          const float* wp = &Wg[wbase + (size_t)((w*8 + tt)*16)*IK];
          const float4 wa = *(const float4*)wp;
          const float4 wb = *(const float4*)(wp + 4);
          uint4 au;
          au.x = bcu(pk2(wa.x, wa.y)); au.y = bcu(pk2(wa.z, wa.w));
          au.z = bcu(pk2(wb.x, wb.y)); au.w = bcu(pk2(wb.z, wb.w));
          acc[tt] = mfma_16x16x32(bch8(au), B, acc[tt]);
        }
      }
    } else {
#pragma unroll 1
      for (int ii = 0; ii < 8; ++ii) {
        const int i = i0 + g8 + ii;
        uint4 bu = {0u,0u,0u,0u};
        if (lg < 2) bu = x_h[ii][lg][lb];     // real K half; rest zero-pad
        const h8 B = bch8(bu);
        uint2 us[8];
        float ap[4] = {0.f, 0.f, 0.f, 0.f};
#pragma unroll
        for (int tt = 0; tt < 8; ++tt) {
          uint4 au = {0u,0u,0u,0u};
          if (lg < 2) {
            const float* wp = &Wg[((size_t)i*ODF + (w*8+tt)*16 + lb)*IK + lg*8];
            const float4 wa = *(const float4*)wp;
            const float4 wb = *(const float4*)(wp + 4);
            au.x = bcu(pk2(wa.x, wa.y)); au.y = bcu(pk2(wa.z, wa.w));
            au.z = bcu(pk2(wb.x, wb.y)); au.w = bcu(pk2(wb.z, wb.w));
          }
          const f4 u = mfma_16x16x32(bch8(au), B, zf);
          const int o = w*4 + (tt >> 1);
          const float4 vv = *(const float4*)
            &vin[((size_t)(bg0 + lb)*OC + o)*OD + (tt & 1)*16 + lg*4];
          ap[tt >> 1] += u.x*vv.x + u.y*vv.y + u.z*vv.z + u.w*vv.w;
          us[tt].x = bcu(pk2(u.x, u.y));      // save u as packed f16
          us[tt].y = bcu(pk2(u.z, u.w));
        }
#pragma unroll
        for (int q = 0; q < 4; ++q) {         // agreement: sum the d-groups
          float a = ap[q];
          a += __shfl_xor(a, 16);
          a += __shfl_xor(a, 32);
          if (l < 16) {
            const int o = w*4 + q;
            float bn = a;
            if (ITER == 2) bn += binT[((size_t)i*OC + o)*NB + bg0 + lb];
            if (ITER == 1) boutT[((size_t)i*OC + o)*NB + bg0 + lb] = bn;
            agr[o][lb] = bn;
          }
        }
        __syncthreads();
        {                                     // softmax: wave w handles b=w
          const float a = agr[l][w];          // o = l
          float m = a;
#pragma unroll
          for (int off = 1; off < 64; off <<= 1) m = fmaxf(m, __shfl_xor(m, off));
          const float e = __expf(a - m);
          float se = e;
#pragma unroll
          for (int off = 1; off < 64; off <<= 1) se += __shfl_xor(se, off);
          c_s[w][l] = e / se;
        }
        __syncthreads();
#pragma unroll
        for (int tt = 0; tt < 8; ++tt) {      // s += c * u  (LDS rmw)
          const int o = w*4 + (tt >> 1);
          const float cm = c_s[lb][o];
          f4* sp = &s_lds[((w*8 + tt)*4 + lg)*16 + lb];
          f4 sv = *sp;
          const h2 p0 = bch2(us[tt].x), p1 = bch2(us[tt].y);
          sv.x += cm * (float)p0.x;
          sv.y += cm * (float)p0.y;
          sv.z += cm * (float)p1.x;
          sv.w += cm * (float)p1.y;
          *sp = sv;
        }
      }
    }
  }

  // flush partial s: cells owned per-thread, no barrier needed
  float* pp = part + (size_t)(ci*2 + bh)*PARTBLK;
#pragma unroll
  for (int tt = 0; tt < 8; ++tt) {
    f4 sv;
    if (ITER == 0) {
      sv = acc[tt];
      sv.x *= (1.f/64.f); sv.y *= (1.f/64.f);
      sv.z *= (1.f/64.f); sv.w *= (1.f/64.f);
    } else {
      sv = s_lds[((w*8 + tt)*4 + lg)*16 + lb];
    }
    float4 st; st.x = sv.x; st.y = sv.y; st.z = sv.z; st.w = sv.w;
    *(float4*)&pp[(size_t)lb*ODF + (w*8 + tt)*16 + lg*4] = st;
  }
}

// Sum the 128 i-chunk partials (per b-half) and apply squash.
// One 64-thr block per (b,o): lanes 0..31 = d, halves split the ci range.
__global__ __launch_bounds__(64)
void caps_reduce(const float* __restrict__ part, float* __restrict__ vout)
{
  const int r  = blockIdx.x;           // b*OC + o
  const int b  = r >> 6, o = r & 63;
  const int bh = b >> 4, bl = b & 15;
  const int d  = threadIdx.x & 31;
  const int h  = threadIdx.x >> 5;
  const float* p = part + (size_t)bh*PARTBLK + (size_t)bl*ODF + o*OD + d;
  float s = 0.f;
#pragma unroll 4
  for (int q = 0; q < NCH/2; ++q)
    s += p[(size_t)((h*(NCH/2) + q)*2)*PARTBLK];
  s += __shfl_xor(s, 32);
  float n2 = s*s;
#pragma unroll
  for (int off = 1; off < 32; off <<= 1) n2 += __shfl_xor(n2, off);
  const float n = sqrtf(n2);
  const float f = n2 / ((1.f + n2)*(n + 1e-8f));   // squash, matches ref
  if (h == 0) vout[(size_t)r*OD + d] = s*f;
}

extern "C" void kernel_launch(void* const* d_in, const int* in_sizes, int n_in,
                              void* d_out, int out_size, void* d_ws, size_t ws_size,
                              hipStream_t stream)
{
  const float* xg = (const float*)d_in[0];
  const float* Wg = (const float*)d_in[1];
  float* out = (float*)d_out;

  const size_t part_bytes = (size_t)NSLOT*PARTBLK*sizeof(float);  // 32 MB
  const size_t bbuf_bytes = (size_t)IC*OC*NB*sizeof(float);       // 16 MB
  float* part = (float*)d_ws;
  float* bbuf = (float*)((char*)d_ws + part_bytes);
  float* vbuf = (float*)((char*)bbuf + bbuf_bytes);
  (void)ws_size;

  // iter 1: c = 1/64 exactly -> pure GEMM, acc in regs
  caps_pass<0><<<NSLOT, 1024, 0, stream>>>(xg, Wg, nullptr, nullptr, nullptr, part);
  caps_reduce<<<NB*OC, 64, 0, stream>>>(part, vbuf);
  // iter 2: A1 = u.v1, c = softmax(A1); store A1 (transposed [i][o][b])
  caps_pass<1><<<NSLOT, 1024, 0, stream>>>(xg, Wg, vbuf, nullptr, bbuf, part);
  caps_reduce<<<NB*OC, 64, 0, stream>>>(part, vbuf);
  // iter 3: c = softmax(A1 + u.v2)
  caps_pass<2><<<NSLOT, 1024, 0, stream>>>(xg, Wg, vbuf, bbuf, nullptr, part);
  caps_reduce<<<NB*OC, 64, 0, stream>>>(part, out);
}